// Round 12
// baseline (30354.086 us; speedup 1.0000x reference)
//
#include <hip/hip_runtime.h>

// Problem constants
#define SEQ   8192
#define VOCAB 256
#define HID   2048
#define ODIM  256
#define NBLK  256   // persistent blocks (1 per CU)
#define NTHR  512   // 8 waves per block
#define JPB   8     // hidden columns owned per block (HID/NBLK)

typedef unsigned int v4u __attribute__((ext_vector_type(4)));

// Issue one 32-B sample (this thread's 4 fp32 (h,epoch) pairs) as two
// coherent dwordx4. NO wait inside -- caller pipelines two samples.
__device__ __forceinline__ void ld2(const void* p, v4u& r0, v4u& r1) {
    asm volatile("global_load_dwordx4 %0, %2, off sc0 sc1\n\t"
                 "global_load_dwordx4 %1, %2, off offset:16 sc0 sc1"
                 : "=&v"(r0), "=&v"(r1) : "v"(p) : "memory");
}
// vmcnt retires in issue order: with 4 loads outstanding, vmcnt(2) means the
// OLDEST sample (r0,r1) has landed. Tying the regs pins their later uses.
__device__ __forceinline__ void wait2(v4u& r0, v4u& r1) {
    asm volatile("s_waitcnt vmcnt(2)" : "+v"(r0), "+v"(r1) :: "memory");
}
// Drain ALL outstanding loads, tying the still-in-flight sample's regs so the
// allocator cannot retire/reuse them before hardware writeback (R8/R10 bug:
// leaving a spin with loads in flight + register pressure = clobber).
__device__ __forceinline__ void drain2(v4u& r0, v4u& r1) {
    asm volatile("s_waitcnt vmcnt(0)" : "+v"(r0), "+v"(r1) :: "memory");
}

// Fast gate math: v_exp_f32 + v_rcp_f32 (~1ulp each)
__device__ __forceinline__ float fsigmoid(float x) {
    return __builtin_amdgcn_rcpf(1.f + __expf(-x));
}
__device__ __forceinline__ float ftanh(float x) {
    x = fminf(20.f, fmaxf(-20.f, x));                 // avoid inf*0 NaN
    float e = __expf(2.f * x);
    return (e - 1.f) * __builtin_amdgcn_rcpf(e + 1.f);
}

// DPP rotate-add within 16-lane rows (proven in R5/R9/R11)
__device__ __forceinline__ float dpp_ror4(float v) {
    return __int_as_float(__builtin_amdgcn_update_dpp(
        0, __float_as_int(v), 0x124, 0xF, 0xF, false));
}
__device__ __forceinline__ float dpp_ror8(float v) {
    return __int_as_float(__builtin_amdgcn_update_dpp(
        0, __float_as_int(v), 0x128, 0xF, 0xF, false));
}
// quad_perm broadcast: every lane receives lane G (0..3) of its aligned quad.
template<int G>
__device__ __forceinline__ float quad_bcast(float v) {
    return __int_as_float(__builtin_amdgcn_update_dpp(
        0, __float_as_int(v), G * 0x55, 0xF, 0xF, false));
}

// ---------------------------------------------------------------------------
// K1: Zv[v][gate][j] = emb[v] @ W_gate[:,j] + b_gate[j] + c_gate[j]
// 256 distinct x values -> whole input projection is an 8 MB lookup table.
// ---------------------------------------------------------------------------
__global__ void k_zv(const float* __restrict__ emb, const float* __restrict__ W,
                     const float* __restrict__ bb, const float* __restrict__ cb,
                     float* __restrict__ Zv, int gate) {
    __shared__ float e[32][VOCAB];
    const int tid = threadIdx.x;
    const int vt = blockIdx.x, ct = blockIdx.y;
    for (int r = 0; r < 32; ++r)
        e[r][tid] = emb[(size_t)(vt * 32 + r) * VOCAB + tid];
    __syncthreads();
    const int j = ct * 256 + tid;
    const float bias = bb[j] + cb[j];
    float acc[32];
#pragma unroll
    for (int r = 0; r < 32; ++r) acc[r] = 0.f;
    for (int u = 0; u < VOCAB; ++u) {
        float w = W[(size_t)u * HID + j];
#pragma unroll
        for (int r = 0; r < 32; ++r) acc[r] += e[r][u] * w;
    }
    for (int r = 0; r < 32; ++r)
        Zv[(size_t)(vt * 32 + r) * (4 * HID) + (size_t)gate * HID + j] = acc[r] + bias;
}

// ---------------------------------------------------------------------------
// K2: persistent cooperative LSTM. R11's proven structure with ONE change:
// the self-draining poll becomes an alternating two-sample pipeline --
// sample A retires via vmcnt(2) while sample B stays in flight, so the
// sampling period is ~RT/2 instead of RT(+sleep). EVERY exit path first
// drains vmcnt(0) with the in-flight sample's registers tied, and hv is
// extracted only after the drain: no register is ever live-while-in-flight
// (R10's crash mode). Register pressure is R11's (group-wise quad fan-out,
// no hq[16]), so the extra 2 v4u fit under the 2-blocks/CU cap.
// Exchange: fp32 (h, epoch32) 8-B pairs at AGENT scope, parity-double-
// buffered (bit-exact h -- lossy exchange diverges, R6/R7).
// Tail: distributed -- wave wv owns hidden column b*8+wv; ONE barrier/step.
// ---------------------------------------------------------------------------
__launch_bounds__(NTHR, 2)
__global__ void k_lstm(const float* __restrict__ Uii, const float* __restrict__ Uff,
                       const float* __restrict__ Ugg, const float* __restrict__ Uoo,
                       const float* __restrict__ Zv,  const int* __restrict__ x,
                       unsigned long long* pub, float* __restrict__ hs,
                       float* __restrict__ outTail) {
    __shared__ __align__(16) float scr2[2][32 * 36];   // 9 KB: parity x chunk x col(+pad)

    const int tid  = threadIdx.x;
    const int b    = blockIdx.x;
    const int gate = tid & 3;
    const int rs   = tid >> 2;              // 0..127: rows [16rs,16rs+16)
    const int lane = tid & 63;
    const int wv   = tid >> 6;
    const int jg   = b * JPB + wv;          // hidden column this WAVE owns

    const float* Ug = (gate == 0) ? Uii : (gate == 1) ? Uff : (gate == 2) ? Ugg : Uoo;

    // U slice -> registers (rows rs*16..+16, cols 8b..8b+8) = 128 f32/thread
    float u[16][JPB];
#pragma unroll
    for (int r = 0; r < 16; ++r) {
        const float4* p = (const float4*)(Ug + (size_t)(rs * 16 + r) * HID + b * JPB);
        float4 a0 = p[0], a1 = p[1];
        u[r][0] = a0.x; u[r][1] = a0.y; u[r][2] = a0.z; u[r][3] = a0.w;
        u[r][4] = a1.x; u[r][5] = a1.y; u[r][6] = a1.z; u[r][7] = a1.w;
    }

    float creg = 0.f;                       // col-jg cell state (all lanes identical)
    unsigned budget = 1u << 22;             // watchdog: bounded spin, fails loudly

    for (int t = 0; t < SEQ; ++t) {
        // Zv prefetch: this lane's gate bias for column jg (overlaps the poll)
        const int xt = x[t];
        float zx = Zv[(size_t)xt * (4 * HID) + (size_t)gate * HID + jg];

        // --- acquire own 4 h cols [4tid,4tid+4): pipelined, drained poll ---
        float4 hv;
        if (t == 0) {
            hv = make_float4(0.f, 0.f, 0.f, 0.f);
        } else {
            const unsigned tgt = (unsigned)t;
            const unsigned long long* sl = pub + (size_t)(t & 1) * HID + tid * 4;
            v4u A0, A1, B0, B1;
            bool useA;
            ld2(sl, A0, A1);                // sample A in flight
            ld2(sl, B0, B1);                // sample B in flight
            for (;;) {
                wait2(A0, A1);              // A landed; B still in flight
                if (((A0.y == tgt) & (A0.w == tgt) &
                     (A1.y == tgt) & (A1.w == tgt)) || budget == 0) {
                    drain2(B0, B1);         // retire B before leaving
                    useA = true; break;
                }
                ld2(sl, A0, A1);            // reissue A (B + newA in flight)
                wait2(B0, B1);              // B landed; newA still in flight
                if (((B0.y == tgt) & (B0.w == tgt) &
                     (B1.y == tgt) & (B1.w == tgt)) || budget == 0) {
                    drain2(A0, A1);         // retire newA before leaving
                    useA = false; break;
                }
                ld2(sl, B0, B1);            // reissue B
                --budget;
                __builtin_amdgcn_s_sleep(1);   // 1 sleep per 2 samples
            }
            // all loads retired here -- extraction is clobber-safe
            if (useA) {
                hv.x = __uint_as_float(A0.x);
                hv.y = __uint_as_float(A0.z);
                hv.z = __uint_as_float(A1.x);
                hv.w = __uint_as_float(A1.z);
            } else {
                hv.x = __uint_as_float(B0.x);
                hv.y = __uint_as_float(B0.z);
                hv.z = __uint_as_float(B1.x);
                hv.w = __uint_as_float(B1.z);
            }
        }

        // --- matvec with in-register quad fan-out (R11-proven) -------------
        // Quad lane g holds h[16rs+4g+i] in hv[i]; group-by-group broadcast
        // (4 live temps) in R9's exact k-order -> bit-identical accumulation.
        float acc[JPB];
#pragma unroll
        for (int jj = 0; jj < JPB; ++jj) acc[jj] = 0.f;
#pragma unroll
        for (int g = 0; g < 4; ++g) {
            float h0, h1, h2, h3;
            if (g == 0) { h0 = quad_bcast<0>(hv.x); h1 = quad_bcast<0>(hv.y);
                          h2 = quad_bcast<0>(hv.z); h3 = quad_bcast<0>(hv.w); }
            else if (g == 1) { h0 = quad_bcast<1>(hv.x); h1 = quad_bcast<1>(hv.y);
                               h2 = quad_bcast<1>(hv.z); h3 = quad_bcast<1>(hv.w); }
            else if (g == 2) { h0 = quad_bcast<2>(hv.x); h1 = quad_bcast<2>(hv.y);
                               h2 = quad_bcast<2>(hv.z); h3 = quad_bcast<2>(hv.w); }
            else { h0 = quad_bcast<3>(hv.x); h1 = quad_bcast<3>(hv.y);
                   h2 = quad_bcast<3>(hv.z); h3 = quad_bcast<3>(hv.w); }
#pragma unroll
            for (int jj = 0; jj < JPB; ++jj)
                acc[jj] += h0 * u[g * 4 + 0][jj];
#pragma unroll
            for (int jj = 0; jj < JPB; ++jj)
                acc[jj] += h1 * u[g * 4 + 1][jj];
#pragma unroll
            for (int jj = 0; jj < JPB; ++jj)
                acc[jj] += h2 * u[g * 4 + 2][jj];
#pragma unroll
            for (int jj = 0; jj < JPB; ++jj)
                acc[jj] += h3 * u[g * 4 + 3][jj];
        }

        // --- DPP reduce: sum the 4 same-gate lanes in each 16-lane row -----
#pragma unroll
        for (int jj = 0; jj < JPB; ++jj) {
            acc[jj] += dpp_ror4(acc[jj]);
            acc[jj] += dpp_ror8(acc[jj]);
        }
        if ((lane & 12) == 0) {             // one writer per (row, gate)
            const int chunk = wv * 4 + (lane >> 4);
            float* p = &scr2[t & 1][chunk * 36 + gate * JPB];
            *(float4*)(p)     = make_float4(acc[0], acc[1], acc[2], acc[3]);
            *(float4*)(p + 4) = make_float4(acc[4], acc[5], acc[6], acc[7]);
        }
        __syncthreads();                    // the ONLY barrier per step

        // --- distributed tail: this wave finishes column jg ----------------
        {
            const int c = lane >> 2;        // 0..15
            const float* s = &scr2[t & 1][0];
            float z = s[c * 36 + gate * JPB + wv] +
                      s[(c + 16) * 36 + gate * JPB + wv];
            z += __shfl_xor(z, 4);          // xor-tree over bits 2..5:
            z += __shfl_xor(z, 8);          //   every lane -> total for its gate
            z += __shfl_xor(z, 16);
            z += __shfl_xor(z, 32);
            z += zx;                        // gate bias (uniform per gate-class)
            float zi = __shfl(z, 0);
            float zf = __shfl(z, 1);
            float zg = __shfl(z, 2);
            float zo = __shfl(z, 3);
            // gates computed redundantly in all lanes (uniform, no divergence)
            float ig = fsigmoid(zi);
            float fg = fsigmoid(zf);
            float gg = ftanh(zg);
            float og = fsigmoid(zo);
            float cn = fg * creg + ig * gg;
            float hn = og * ftanh(cn);
            creg = cn;
            if (lane == 0) {
                // publish FIRST (critical path)
                unsigned long long pk =
                    ((unsigned long long)(unsigned)(t + 1) << 32) | __float_as_uint(hn);
                __hip_atomic_store(&pub[(size_t)((t + 1) & 1) * HID + jg], pk,
                                   __ATOMIC_RELAXED, __HIP_MEMORY_SCOPE_AGENT);
                hs[(size_t)t * HID + jg] = hn;
                if (t == SEQ - 1) { outTail[jg] = hn; outTail[HID + jg] = cn; }
            }
        }
    }
}

// ---------------------------------------------------------------------------
// K3: out[t][o] = hs[t] @ V_w[:,o] + V_b[o].
// ---------------------------------------------------------------------------
__global__ void k_out(const float* __restrict__ hs, const float* __restrict__ Vw,
                      const float* __restrict__ Vb, float* __restrict__ out) {
    __shared__ float tile[32][64];
    const int tid = threadIdx.x;
    const int t0 = blockIdx.x * 32;
    float acc[32];
#pragma unroll
    for (int r = 0; r < 32; ++r) acc[r] = 0.f;
    for (int k0 = 0; k0 < HID; k0 += 64) {
        {
            const int r = tid >> 3, kk = (tid & 7) * 8;
            const float4* p = (const float4*)(hs + (size_t)(t0 + r) * HID + k0 + kk);
            float4 a = p[0], bq = p[1];
            *(float4*)&tile[r][kk]     = a;
            *(float4*)&tile[r][kk + 4] = bq;
        }
        __syncthreads();
        for (int kk = 0; kk < 64; ++kk) {
            float w = Vw[(size_t)(k0 + kk) * ODIM + tid];
#pragma unroll
            for (int r = 0; r < 32; ++r) acc[r] += tile[r][kk] * w;
        }
        __syncthreads();
    }
    const float vb = Vb[tid];
    for (int r = 0; r < 32; ++r)
        out[(size_t)(t0 + r) * ODIM + tid] = acc[r] + vb;
}

// ---------------------------------------------------------------------------
extern "C" void kernel_launch(void* const* d_in, const int* in_sizes, int n_in,
                              void* d_out, int out_size, void* d_ws, size_t ws_size,
                              hipStream_t stream) {
    const int*   x   = (const int*)d_in[0];
    const float* emb = (const float*)d_in[1];
    const float* W[4] = {(const float*)d_in[2], (const float*)d_in[6],
                         (const float*)d_in[10], (const float*)d_in[14]};
    const float* B[4] = {(const float*)d_in[3], (const float*)d_in[7],
                         (const float*)d_in[11], (const float*)d_in[15]};
    const float* U[4] = {(const float*)d_in[4], (const float*)d_in[8],
                         (const float*)d_in[12], (const float*)d_in[16]};
    const float* C[4] = {(const float*)d_in[5], (const float*)d_in[9],
                         (const float*)d_in[13], (const float*)d_in[17]};
    const float* Vw = (const float*)d_in[18];
    const float* Vb = (const float*)d_in[19];
    float* out = (float*)d_out;

    // ws layout (floats): Zv[256*4*2048] | hs[8192*2048] | pub[2*2048 ull].
    // Poison epoch word 0xAAAAAAAA never equals a live epoch (1..8192), and
    // ws is re-poisoned before every timed call -> no init kernel needed.
    float* ws = (float*)d_ws;
    float* Zv = ws;
    float* hs = Zv + (size_t)VOCAB * 4 * HID;
    unsigned long long* pub = (unsigned long long*)(hs + (size_t)SEQ * HID);

    for (int g = 0; g < 4; ++g)
        k_zv<<<dim3(8, 8), dim3(256), 0, stream>>>(emb, W[g], B[g], C[g], Zv, g);

    float* outTail = out + (size_t)SEQ * ODIM;
    const float *Ui = U[0], *Uf = U[1], *Ugp = U[2], *Uo = U[3];
    const float* Zvc = Zv; const int* xc = x;
    unsigned long long* pubc = pub; float* hsc = hs; float* ot = outTail;
    void* args[9] = {&Ui, &Uf, &Ugp, &Uo, &Zvc, &xc, &pubc, &hsc, &ot};
    hipLaunchCooperativeKernel((void*)k_lstm, dim3(NBLK), dim3(NTHR), args, 0, stream);

    k_out<<<dim3(256), dim3(256), 0, stream>>>(hs, Vw, Vb, out);
}

// Round 13
// 17666.527 us; speedup vs baseline: 1.7182x; 1.7182x over previous
//
#include <hip/hip_runtime.h>

// Problem constants
#define SEQ   8192
#define VOCAB 256
#define HID   2048
#define ODIM  256
#define NBLK  256   // persistent blocks (1 per CU)
#define NTHR  512   // 8 waves per block
#define JPB   8     // hidden columns owned per block (HID/NBLK)

typedef unsigned int v4u __attribute__((ext_vector_type(4)));

// Read this thread's 4 (h,epoch32) fp32 pairs (32 B) as two coherent dwordx4
// with the drain INSIDE the asm block: no load is ever in flight when control
// leaves the block. R10/R12 proved every pipelined variant either clobbers
// registers or congests the MALL -- this self-draining shape is the proven
// optimum. sc0 sc1 = bypass L1/L2, read the device coherence point.
__device__ __forceinline__ void ld32_coh_sync(const void* p, v4u& r0, v4u& r1) {
    asm volatile("global_load_dwordx4 %0, %2, off sc0 sc1\n\t"
                 "global_load_dwordx4 %1, %2, off offset:16 sc0 sc1\n\t"
                 "s_waitcnt vmcnt(0)"
                 : "=&v"(r0), "=&v"(r1) : "v"(p) : "memory");
}

// Fast gate math: v_exp_f32 + v_rcp_f32 (~1ulp each)
__device__ __forceinline__ float fsigmoid(float x) {
    return __builtin_amdgcn_rcpf(1.f + __expf(-x));
}
__device__ __forceinline__ float ftanh(float x) {
    x = fminf(20.f, fmaxf(-20.f, x));                 // avoid inf*0 NaN
    float e = __expf(2.f * x);
    return (e - 1.f) * __builtin_amdgcn_rcpf(e + 1.f);
}

// DPP rotate-add within 16-lane rows (proven in R5/R9/R11)
__device__ __forceinline__ float dpp_ror4(float v) {
    return __int_as_float(__builtin_amdgcn_update_dpp(
        0, __float_as_int(v), 0x124, 0xF, 0xF, false));
}
__device__ __forceinline__ float dpp_ror8(float v) {
    return __int_as_float(__builtin_amdgcn_update_dpp(
        0, __float_as_int(v), 0x128, 0xF, 0xF, false));
}
// quad_perm broadcast: every lane receives lane G (0..3) of its aligned quad.
template<int G>
__device__ __forceinline__ float quad_bcast(float v) {
    return __int_as_float(__builtin_amdgcn_update_dpp(
        0, __float_as_int(v), G * 0x55, 0xF, 0xF, false));
}

// ---------------------------------------------------------------------------
// K1: Zv[v][gate][j] = emb[v] @ W_gate[:,j] + b_gate[j] + c_gate[j]
// 256 distinct x values -> whole input projection is an 8 MB lookup table.
// ---------------------------------------------------------------------------
__global__ void k_zv(const float* __restrict__ emb, const float* __restrict__ W,
                     const float* __restrict__ bb, const float* __restrict__ cb,
                     float* __restrict__ Zv, int gate) {
    __shared__ float e[32][VOCAB];
    const int tid = threadIdx.x;
    const int vt = blockIdx.x, ct = blockIdx.y;
    for (int r = 0; r < 32; ++r)
        e[r][tid] = emb[(size_t)(vt * 32 + r) * VOCAB + tid];
    __syncthreads();
    const int j = ct * 256 + tid;
    const float bias = bb[j] + cb[j];
    float acc[32];
#pragma unroll
    for (int r = 0; r < 32; ++r) acc[r] = 0.f;
    for (int u = 0; u < VOCAB; ++u) {
        float w = W[(size_t)u * HID + j];
#pragma unroll
        for (int r = 0; r < 32; ++r) acc[r] += e[r][u] * w;
    }
    for (int r = 0; r < 32; ++r)
        Zv[(size_t)(vt * 32 + r) * (4 * HID) + (size_t)gate * HID + j] = acc[r] + bias;
}

// ---------------------------------------------------------------------------
// K2: persistent cooperative LSTM -- R11 VERBATIM (proven 16.55 ms, absmax
// 0.00390625). Exchange: fp32 (h, epoch32) 8-B pairs at AGENT scope, parity-
// double-buffered; self-draining 32-B poll + s_sleep(1); quad_perm fan-out
// (group-wise, low register pressure); DPP reduce; ONE barrier/step;
// distributed per-wave tail.
// ---------------------------------------------------------------------------
__launch_bounds__(NTHR, 2)
__global__ void k_lstm(const float* __restrict__ Uii, const float* __restrict__ Uff,
                       const float* __restrict__ Ugg, const float* __restrict__ Uoo,
                       const float* __restrict__ Zv,  const int* __restrict__ x,
                       unsigned long long* pub, float* __restrict__ hs,
                       float* __restrict__ outTail) {
    __shared__ __align__(16) float scr2[2][32 * 36];   // 9 KB: parity x chunk x col(+pad)

    const int tid  = threadIdx.x;
    const int b    = blockIdx.x;
    const int gate = tid & 3;
    const int rs   = tid >> 2;              // 0..127: rows [16rs,16rs+16)
    const int lane = tid & 63;
    const int wv   = tid >> 6;
    const int jg   = b * JPB + wv;          // hidden column this WAVE owns

    const float* Ug = (gate == 0) ? Uii : (gate == 1) ? Uff : (gate == 2) ? Ugg : Uoo;

    // U slice -> registers (rows rs*16..+16, cols 8b..8b+8) = 128 f32/thread
    float u[16][JPB];
#pragma unroll
    for (int r = 0; r < 16; ++r) {
        const float4* p = (const float4*)(Ug + (size_t)(rs * 16 + r) * HID + b * JPB);
        float4 a0 = p[0], a1 = p[1];
        u[r][0] = a0.x; u[r][1] = a0.y; u[r][2] = a0.z; u[r][3] = a0.w;
        u[r][4] = a1.x; u[r][5] = a1.y; u[r][6] = a1.z; u[r][7] = a1.w;
    }

    float creg = 0.f;                       // col-jg cell state (all lanes identical)
    unsigned budget = 1u << 22;             // watchdog: bounded spin, fails loudly

    for (int t = 0; t < SEQ; ++t) {
        // Zv prefetch: this lane's gate bias for column jg (overlaps the poll)
        const int xt = x[t];
        float zx = Zv[(size_t)xt * (4 * HID) + (size_t)gate * HID + jg];

        // --- acquire own 4 h cols [4tid,4tid+4): self-draining poll --------
        float4 hv;
        if (t == 0) {
            hv = make_float4(0.f, 0.f, 0.f, 0.f);
        } else {
            const unsigned tgt = (unsigned)t;
            const unsigned long long* sl = pub + (size_t)(t & 1) * HID + tid * 4;
            v4u A0, A1;
            for (;;) {
                ld32_coh_sync(sl, A0, A1);  // 2 requests, drained in-block
                if (((A0.y == tgt) & (A0.w == tgt) &
                     (A1.y == tgt) & (A1.w == tgt)) || budget == 0) break;
                --budget;
                __builtin_amdgcn_s_sleep(1);
            }
            hv.x = __uint_as_float(A0.x);   // pair = (h lo-word, epoch hi-word)
            hv.y = __uint_as_float(A0.z);
            hv.z = __uint_as_float(A1.x);
            hv.w = __uint_as_float(A1.z);
        }

        // --- matvec with in-register quad fan-out (R11-proven) -------------
        float acc[JPB];
#pragma unroll
        for (int jj = 0; jj < JPB; ++jj) acc[jj] = 0.f;
#pragma unroll
        for (int g = 0; g < 4; ++g) {
            float h0, h1, h2, h3;
            if (g == 0) { h0 = quad_bcast<0>(hv.x); h1 = quad_bcast<0>(hv.y);
                          h2 = quad_bcast<0>(hv.z); h3 = quad_bcast<0>(hv.w); }
            else if (g == 1) { h0 = quad_bcast<1>(hv.x); h1 = quad_bcast<1>(hv.y);
                               h2 = quad_bcast<1>(hv.z); h3 = quad_bcast<1>(hv.w); }
            else if (g == 2) { h0 = quad_bcast<2>(hv.x); h1 = quad_bcast<2>(hv.y);
                               h2 = quad_bcast<2>(hv.z); h3 = quad_bcast<2>(hv.w); }
            else { h0 = quad_bcast<3>(hv.x); h1 = quad_bcast<3>(hv.y);
                   h2 = quad_bcast<3>(hv.z); h3 = quad_bcast<3>(hv.w); }
#pragma unroll
            for (int jj = 0; jj < JPB; ++jj)
                acc[jj] += h0 * u[g * 4 + 0][jj];
#pragma unroll
            for (int jj = 0; jj < JPB; ++jj)
                acc[jj] += h1 * u[g * 4 + 1][jj];
#pragma unroll
            for (int jj = 0; jj < JPB; ++jj)
                acc[jj] += h2 * u[g * 4 + 2][jj];
#pragma unroll
            for (int jj = 0; jj < JPB; ++jj)
                acc[jj] += h3 * u[g * 4 + 3][jj];
        }

        // --- DPP reduce: sum the 4 same-gate lanes in each 16-lane row -----
#pragma unroll
        for (int jj = 0; jj < JPB; ++jj) {
            acc[jj] += dpp_ror4(acc[jj]);
            acc[jj] += dpp_ror8(acc[jj]);
        }
        if ((lane & 12) == 0) {             // one writer per (row, gate)
            const int chunk = wv * 4 + (lane >> 4);
            float* p = &scr2[t & 1][chunk * 36 + gate * JPB];
            *(float4*)(p)     = make_float4(acc[0], acc[1], acc[2], acc[3]);
            *(float4*)(p + 4) = make_float4(acc[4], acc[5], acc[6], acc[7]);
        }
        __syncthreads();                    // the ONLY barrier per step

        // --- distributed tail: this wave finishes column jg ----------------
        {
            const int c = lane >> 2;        // 0..15
            const float* s = &scr2[t & 1][0];
            float z = s[c * 36 + gate * JPB + wv] +
                      s[(c + 16) * 36 + gate * JPB + wv];
            z += __shfl_xor(z, 4);          // xor-tree over bits 2..5:
            z += __shfl_xor(z, 8);          //   every lane -> total for its gate
            z += __shfl_xor(z, 16);
            z += __shfl_xor(z, 32);
            z += zx;                        // gate bias (uniform per gate-class)
            float zi = __shfl(z, 0);
            float zf = __shfl(z, 1);
            float zg = __shfl(z, 2);
            float zo = __shfl(z, 3);
            // gates computed redundantly in all lanes (uniform, no divergence)
            float ig = fsigmoid(zi);
            float fg = fsigmoid(zf);
            float gg = ftanh(zg);
            float og = fsigmoid(zo);
            float cn = fg * creg + ig * gg;
            float hn = og * ftanh(cn);
            creg = cn;
            if (lane == 0) {
                // publish FIRST (critical path)
                unsigned long long pk =
                    ((unsigned long long)(unsigned)(t + 1) << 32) | __float_as_uint(hn);
                __hip_atomic_store(&pub[(size_t)((t + 1) & 1) * HID + jg], pk,
                                   __ATOMIC_RELAXED, __HIP_MEMORY_SCOPE_AGENT);
                hs[(size_t)t * HID + jg] = hn;
                if (t == SEQ - 1) { outTail[jg] = hn; outTail[HID + jg] = cn; }
            }
        }
    }
}

// ---------------------------------------------------------------------------
// K3: out[t][o] = hs[t] @ V_w[:,o] + V_b[o]. REWRITTEN: the old version did
// 65K scalar ds_read broadcasts per wave (LDS-pipe bound, ~1 ms). Now:
// 256 blocks x 256 threads as 16 row-groups (ti, 2 rows each) x 16 col-
// groups (tj, 16 cols each); acc[2][16] in registers; hs staged per 32-k
// tile in padded LDS and read as ds_read_b128 (8x fewer LDS ops, b128);
// Vw read coalesced from L2 as float4. VALU-bound: ~55 us floor.
// Accumulation remains ascending-kk order.
// ---------------------------------------------------------------------------
__global__ void k_out(const float* __restrict__ hs, const float* __restrict__ Vw,
                      const float* __restrict__ Vb, float* __restrict__ out) {
    __shared__ __align__(16) float tile[32][36];   // 32 rows x 32 k (+4 pad), 4.6 KB
    const int tid = threadIdx.x;
    const int tj  = tid & 15;               // col group: cols 16tj..16tj+16
    const int ti  = tid >> 4;               // row group: rows 2ti..2ti+2
    const int t0  = blockIdx.x * 32;

    float acc[2][16];
#pragma unroll
    for (int r = 0; r < 2; ++r)
#pragma unroll
        for (int c = 0; c < 16; ++c) acc[r][c] = 0.f;

    for (int k0 = 0; k0 < HID; k0 += 32) {
        {   // stage hs[t0..t0+32)[k0..k0+32) -- 4 floats/thread, coalesced
            const int r = tid >> 3, kk = (tid & 7) * 4;
            *(float4*)&tile[r][kk] =
                *(const float4*)(hs + (size_t)(t0 + r) * HID + k0 + kk);
        }
        __syncthreads();
#pragma unroll
        for (int kq = 0; kq < 8; ++kq) {    // 4 kk per group
            // h for this thread's 2 rows, 4 k's: two b128 broadcast reads
            float4 h0 = *(const float4*)&tile[2 * ti][kq * 4];
            float4 h1 = *(const float4*)&tile[2 * ti + 1][kq * 4];
            const float* wp = Vw + (size_t)(k0 + kq * 4) * ODIM + tj * 16;
#pragma unroll
            for (int i = 0; i < 4; ++i) {   // kk = kq*4 + i, ascending
                float4 w0 = *(const float4*)(wp + (size_t)i * ODIM);
                float4 w1 = *(const float4*)(wp + (size_t)i * ODIM + 4);
                float4 w2 = *(const float4*)(wp + (size_t)i * ODIM + 8);
                float4 w3 = *(const float4*)(wp + (size_t)i * ODIM + 12);
                float ha = (i == 0) ? h0.x : (i == 1) ? h0.y : (i == 2) ? h0.z : h0.w;
                float hb = (i == 0) ? h1.x : (i == 1) ? h1.y : (i == 2) ? h1.z : h1.w;
                acc[0][0]  += ha * w0.x; acc[0][1]  += ha * w0.y;
                acc[0][2]  += ha * w0.z; acc[0][3]  += ha * w0.w;
                acc[0][4]  += ha * w1.x; acc[0][5]  += ha * w1.y;
                acc[0][6]  += ha * w1.z; acc[0][7]  += ha * w1.w;
                acc[0][8]  += ha * w2.x; acc[0][9]  += ha * w2.y;
                acc[0][10] += ha * w2.z; acc[0][11] += ha * w2.w;
                acc[0][12] += ha * w3.x; acc[0][13] += ha * w3.y;
                acc[0][14] += ha * w3.z; acc[0][15] += ha * w3.w;
                acc[1][0]  += hb * w0.x; acc[1][1]  += hb * w0.y;
                acc[1][2]  += hb * w0.z; acc[1][3]  += hb * w0.w;
                acc[1][4]  += hb * w1.x; acc[1][5]  += hb * w1.y;
                acc[1][6]  += hb * w1.z; acc[1][7]  += hb * w1.w;
                acc[1][8]  += hb * w2.x; acc[1][9]  += hb * w2.y;
                acc[1][10] += hb * w2.z; acc[1][11] += hb * w2.w;
                acc[1][12] += hb * w3.x; acc[1][13] += hb * w3.y;
                acc[1][14] += hb * w3.z; acc[1][15] += hb * w3.w;
            }
        }
        __syncthreads();
    }
#pragma unroll
    for (int r = 0; r < 2; ++r) {
        float* op = out + (size_t)(t0 + 2 * ti + r) * ODIM + tj * 16;
        const float* vb = Vb + tj * 16;
#pragma unroll
        for (int c4 = 0; c4 < 4; ++c4) {
            float4 v = *(const float4*)(vb + c4 * 4);
            *(float4*)(op + c4 * 4) = make_float4(
                acc[r][c4 * 4 + 0] + v.x, acc[r][c4 * 4 + 1] + v.y,
                acc[r][c4 * 4 + 2] + v.z, acc[r][c4 * 4 + 3] + v.w);
        }
    }
}

// ---------------------------------------------------------------------------
extern "C" void kernel_launch(void* const* d_in, const int* in_sizes, int n_in,
                              void* d_out, int out_size, void* d_ws, size_t ws_size,
                              hipStream_t stream) {
    const int*   x   = (const int*)d_in[0];
    const float* emb = (const float*)d_in[1];
    const float* W[4] = {(const float*)d_in[2], (const float*)d_in[6],
                         (const float*)d_in[10], (const float*)d_in[14]};
    const float* B[4] = {(const float*)d_in[3], (const float*)d_in[7],
                         (const float*)d_in[11], (const float*)d_in[15]};
    const float* U[4] = {(const float*)d_in[4], (const float*)d_in[8],
                         (const float*)d_in[12], (const float*)d_in[16]};
    const float* C[4] = {(const float*)d_in[5], (const float*)d_in[9],
                         (const float*)d_in[13], (const float*)d_in[17]};
    const float* Vw = (const float*)d_in[18];
    const float* Vb = (const float*)d_in[19];
    float* out = (float*)d_out;

    // ws layout (floats): Zv[256*4*2048] | hs[8192*2048] | pub[2*2048 ull].
    // Poison epoch word 0xAAAAAAAA never equals a live epoch (1..8192), and
    // ws is re-poisoned before every timed call -> no init kernel needed.
    float* ws = (float*)d_ws;
    float* Zv = ws;
    float* hs = Zv + (size_t)VOCAB * 4 * HID;
    unsigned long long* pub = (unsigned long long*)(hs + (size_t)SEQ * HID);

    for (int g = 0; g < 4; ++g)
        k_zv<<<dim3(8, 8), dim3(256), 0, stream>>>(emb, W[g], B[g], C[g], Zv, g);

    float* outTail = out + (size_t)SEQ * ODIM;
    const float *Ui = U[0], *Uf = U[1], *Ugp = U[2], *Uo = U[3];
    const float* Zvc = Zv; const int* xc = x;
    unsigned long long* pubc = pub; float* hsc = hs; float* ot = outTail;
    void* args[9] = {&Ui, &Uf, &Ugp, &Uo, &Zvc, &xc, &pubc, &hsc, &ot};
    hipLaunchCooperativeKernel((void*)k_lstm, dim3(NBLK), dim3(NTHR), args, 0, stream);

    k_out<<<dim3(256), dim3(256), 0, stream>>>(hs, Vw, Vb, out);
}

// Round 14
// 17659.448 us; speedup vs baseline: 1.7189x; 1.0004x over previous
//
#include <hip/hip_runtime.h>

// Problem constants
#define SEQ   8192
#define VOCAB 256
#define HID   2048
#define ODIM  256
#define NBLK  256   // persistent blocks (1 per CU)
#define NTHR  512   // 8 waves per block
#define JPB   8     // hidden columns owned per block (HID/NBLK)

typedef unsigned int v4u __attribute__((ext_vector_type(4)));

// Read this thread's 4 (h,epoch32) fp32 pairs (32 B) as two coherent dwordx4
// with the drain INSIDE the asm block: no load is ever in flight when control
// leaves the block. R10/R12 proved every pipelined variant either clobbers
// registers or congests the MALL -- this self-draining shape is the proven
// optimum. sc0 sc1 = bypass L1/L2, read the device coherence point.
__device__ __forceinline__ void ld32_coh_sync(const void* p, v4u& r0, v4u& r1) {
    asm volatile("global_load_dwordx4 %0, %2, off sc0 sc1\n\t"
                 "global_load_dwordx4 %1, %2, off offset:16 sc0 sc1\n\t"
                 "s_waitcnt vmcnt(0)"
                 : "=&v"(r0), "=&v"(r1) : "v"(p) : "memory");
}

// Fast gate math: v_exp_f32 + v_rcp_f32 (~1ulp each)
__device__ __forceinline__ float fsigmoid(float x) {
    return __builtin_amdgcn_rcpf(1.f + __expf(-x));
}
__device__ __forceinline__ float ftanh(float x) {
    x = fminf(20.f, fmaxf(-20.f, x));                 // avoid inf*0 NaN
    float e = __expf(2.f * x);
    return (e - 1.f) * __builtin_amdgcn_rcpf(e + 1.f);
}

// DPP rotate-add within 16-lane rows (proven in R5/R9/R11)
__device__ __forceinline__ float dpp_ror4(float v) {
    return __int_as_float(__builtin_amdgcn_update_dpp(
        0, __float_as_int(v), 0x124, 0xF, 0xF, false));
}
__device__ __forceinline__ float dpp_ror8(float v) {
    return __int_as_float(__builtin_amdgcn_update_dpp(
        0, __float_as_int(v), 0x128, 0xF, 0xF, false));
}
// quad_perm broadcast: every lane receives lane G (0..3) of its aligned quad.
template<int G>
__device__ __forceinline__ float quad_bcast(float v) {
    return __int_as_float(__builtin_amdgcn_update_dpp(
        0, __float_as_int(v), G * 0x55, 0xF, 0xF, false));
}

// ---------------------------------------------------------------------------
// K1: Zv[v][gate][j] = emb[v] @ W_gate[:,j] + b_gate[j] + c_gate[j]
// 256 distinct x values -> whole input projection is an 8 MB lookup table.
// ---------------------------------------------------------------------------
__global__ void k_zv(const float* __restrict__ emb, const float* __restrict__ W,
                     const float* __restrict__ bb, const float* __restrict__ cb,
                     float* __restrict__ Zv, int gate) {
    __shared__ float e[32][VOCAB];
    const int tid = threadIdx.x;
    const int vt = blockIdx.x, ct = blockIdx.y;
    for (int r = 0; r < 32; ++r)
        e[r][tid] = emb[(size_t)(vt * 32 + r) * VOCAB + tid];
    __syncthreads();
    const int j = ct * 256 + tid;
    const float bias = bb[j] + cb[j];
    float acc[32];
#pragma unroll
    for (int r = 0; r < 32; ++r) acc[r] = 0.f;
    for (int u = 0; u < VOCAB; ++u) {
        float w = W[(size_t)u * HID + j];
#pragma unroll
        for (int r = 0; r < 32; ++r) acc[r] += e[r][u] * w;
    }
    for (int r = 0; r < 32; ++r)
        Zv[(size_t)(vt * 32 + r) * (4 * HID) + (size_t)gate * HID + j] = acc[r] + bias;
}

// ---------------------------------------------------------------------------
// K2: persistent cooperative LSTM -- R13 structure (proven 16.57 ms typical,
// absmax 0.00390625) with ONE change: per-block sleep-period diversity in the
// poll loop. Every passing round showed bimodal dispatches (16.5 ms typical,
// 36-46 ms outliers) -- the signature of metastable sampling lockstep when
// all 256 blocks poll with identical periods. Blocks now sleep 1 or 2 units
// by block parity (wave-uniform branch): heterogeneous periods cannot stay
// phase-locked, at a cost of <=13 ns/step for the slower half.
// ---------------------------------------------------------------------------
__launch_bounds__(NTHR, 2)
__global__ void k_lstm(const float* __restrict__ Uii, const float* __restrict__ Uff,
                       const float* __restrict__ Ugg, const float* __restrict__ Uoo,
                       const float* __restrict__ Zv,  const int* __restrict__ x,
                       unsigned long long* pub, float* __restrict__ hs,
                       float* __restrict__ outTail) {
    __shared__ __align__(16) float scr2[2][32 * 36];   // 9 KB: parity x chunk x col(+pad)

    const int tid  = threadIdx.x;
    const int b    = blockIdx.x;
    const int gate = tid & 3;
    const int rs   = tid >> 2;              // 0..127: rows [16rs,16rs+16)
    const int lane = tid & 63;
    const int wv   = tid >> 6;
    const int jg   = b * JPB + wv;          // hidden column this WAVE owns
    const bool slowClk = (b & 1);           // period diversity class

    const float* Ug = (gate == 0) ? Uii : (gate == 1) ? Uff : (gate == 2) ? Ugg : Uoo;

    // U slice -> registers (rows rs*16..+16, cols 8b..8b+8) = 128 f32/thread
    float u[16][JPB];
#pragma unroll
    for (int r = 0; r < 16; ++r) {
        const float4* p = (const float4*)(Ug + (size_t)(rs * 16 + r) * HID + b * JPB);
        float4 a0 = p[0], a1 = p[1];
        u[r][0] = a0.x; u[r][1] = a0.y; u[r][2] = a0.z; u[r][3] = a0.w;
        u[r][4] = a1.x; u[r][5] = a1.y; u[r][6] = a1.z; u[r][7] = a1.w;
    }

    float creg = 0.f;                       // col-jg cell state (all lanes identical)
    unsigned budget = 1u << 22;             // watchdog: bounded spin, fails loudly

    for (int t = 0; t < SEQ; ++t) {
        // Zv prefetch: this lane's gate bias for column jg (overlaps the poll)
        const int xt = x[t];
        float zx = Zv[(size_t)xt * (4 * HID) + (size_t)gate * HID + jg];

        // --- acquire own 4 h cols [4tid,4tid+4): self-draining poll --------
        float4 hv;
        if (t == 0) {
            hv = make_float4(0.f, 0.f, 0.f, 0.f);
        } else {
            const unsigned tgt = (unsigned)t;
            const unsigned long long* sl = pub + (size_t)(t & 1) * HID + tid * 4;
            v4u A0, A1;
            for (;;) {
                ld32_coh_sync(sl, A0, A1);  // 2 requests, drained in-block
                if (((A0.y == tgt) & (A0.w == tgt) &
                     (A1.y == tgt) & (A1.w == tgt)) || budget == 0) break;
                --budget;
                if (slowClk) __builtin_amdgcn_s_sleep(2);   // desync: two
                else         __builtin_amdgcn_s_sleep(1);   // period classes
            }
            hv.x = __uint_as_float(A0.x);   // pair = (h lo-word, epoch hi-word)
            hv.y = __uint_as_float(A0.z);
            hv.z = __uint_as_float(A1.x);
            hv.w = __uint_as_float(A1.z);
        }

        // --- matvec with in-register quad fan-out (R11-proven) -------------
        float acc[JPB];
#pragma unroll
        for (int jj = 0; jj < JPB; ++jj) acc[jj] = 0.f;
#pragma unroll
        for (int g = 0; g < 4; ++g) {
            float h0, h1, h2, h3;
            if (g == 0) { h0 = quad_bcast<0>(hv.x); h1 = quad_bcast<0>(hv.y);
                          h2 = quad_bcast<0>(hv.z); h3 = quad_bcast<0>(hv.w); }
            else if (g == 1) { h0 = quad_bcast<1>(hv.x); h1 = quad_bcast<1>(hv.y);
                               h2 = quad_bcast<1>(hv.z); h3 = quad_bcast<1>(hv.w); }
            else if (g == 2) { h0 = quad_bcast<2>(hv.x); h1 = quad_bcast<2>(hv.y);
                               h2 = quad_bcast<2>(hv.z); h3 = quad_bcast<2>(hv.w); }
            else { h0 = quad_bcast<3>(hv.x); h1 = quad_bcast<3>(hv.y);
                   h2 = quad_bcast<3>(hv.z); h3 = quad_bcast<3>(hv.w); }
#pragma unroll
            for (int jj = 0; jj < JPB; ++jj)
                acc[jj] += h0 * u[g * 4 + 0][jj];
#pragma unroll
            for (int jj = 0; jj < JPB; ++jj)
                acc[jj] += h1 * u[g * 4 + 1][jj];
#pragma unroll
            for (int jj = 0; jj < JPB; ++jj)
                acc[jj] += h2 * u[g * 4 + 2][jj];
#pragma unroll
            for (int jj = 0; jj < JPB; ++jj)
                acc[jj] += h3 * u[g * 4 + 3][jj];
        }

        // --- DPP reduce: sum the 4 same-gate lanes in each 16-lane row -----
#pragma unroll
        for (int jj = 0; jj < JPB; ++jj) {
            acc[jj] += dpp_ror4(acc[jj]);
            acc[jj] += dpp_ror8(acc[jj]);
        }
        if ((lane & 12) == 0) {             // one writer per (row, gate)
            const int chunk = wv * 4 + (lane >> 4);
            float* p = &scr2[t & 1][chunk * 36 + gate * JPB];
            *(float4*)(p)     = make_float4(acc[0], acc[1], acc[2], acc[3]);
            *(float4*)(p + 4) = make_float4(acc[4], acc[5], acc[6], acc[7]);
        }
        __syncthreads();                    // the ONLY barrier per step

        // --- distributed tail: this wave finishes column jg ----------------
        {
            const int c = lane >> 2;        // 0..15
            const float* s = &scr2[t & 1][0];
            float z = s[c * 36 + gate * JPB + wv] +
                      s[(c + 16) * 36 + gate * JPB + wv];
            z += __shfl_xor(z, 4);          // xor-tree over bits 2..5:
            z += __shfl_xor(z, 8);          //   every lane -> total for its gate
            z += __shfl_xor(z, 16);
            z += __shfl_xor(z, 32);
            z += zx;                        // gate bias (uniform per gate-class)
            float zi = __shfl(z, 0);
            float zf = __shfl(z, 1);
            float zg = __shfl(z, 2);
            float zo = __shfl(z, 3);
            // gates computed redundantly in all lanes (uniform, no divergence)
            float ig = fsigmoid(zi);
            float fg = fsigmoid(zf);
            float gg = ftanh(zg);
            float og = fsigmoid(zo);
            float cn = fg * creg + ig * gg;
            float hn = og * ftanh(cn);
            creg = cn;
            if (lane == 0) {
                // publish FIRST (critical path)
                unsigned long long pk =
                    ((unsigned long long)(unsigned)(t + 1) << 32) | __float_as_uint(hn);
                __hip_atomic_store(&pub[(size_t)((t + 1) & 1) * HID + jg], pk,
                                   __ATOMIC_RELAXED, __HIP_MEMORY_SCOPE_AGENT);
                hs[(size_t)t * HID + jg] = hn;
                if (t == SEQ - 1) { outTail[jg] = hn; outTail[HID + jg] = cn; }
            }
        }
    }
}

// ---------------------------------------------------------------------------
// K3: out[t][o] = hs[t] @ V_w[:,o] + V_b[o]. Register-tiled (R13-proven):
// acc[2][16]/thread, hs staged per 32-k tile in padded LDS (b128 reads),
// Vw coalesced float4 from L2. VALU-bound, ~0.15 ms.
// ---------------------------------------------------------------------------
__global__ void k_out(const float* __restrict__ hs, const float* __restrict__ Vw,
                      const float* __restrict__ Vb, float* __restrict__ out) {
    __shared__ __align__(16) float tile[32][36];   // 32 rows x 32 k (+4 pad), 4.6 KB
    const int tid = threadIdx.x;
    const int tj  = tid & 15;               // col group: cols 16tj..16tj+16
    const int ti  = tid >> 4;               // row group: rows 2ti..2ti+2
    const int t0  = blockIdx.x * 32;

    float acc[2][16];
#pragma unroll
    for (int r = 0; r < 2; ++r)
#pragma unroll
        for (int c = 0; c < 16; ++c) acc[r][c] = 0.f;

    for (int k0 = 0; k0 < HID; k0 += 32) {
        {   // stage hs[t0..t0+32)[k0..k0+32) -- 4 floats/thread, coalesced
            const int r = tid >> 3, kk = (tid & 7) * 4;
            *(float4*)&tile[r][kk] =
                *(const float4*)(hs + (size_t)(t0 + r) * HID + k0 + kk);
        }
        __syncthreads();
#pragma unroll
        for (int kq = 0; kq < 8; ++kq) {    // 4 kk per group
            float4 h0 = *(const float4*)&tile[2 * ti][kq * 4];
            float4 h1 = *(const float4*)&tile[2 * ti + 1][kq * 4];
            const float* wp = Vw + (size_t)(k0 + kq * 4) * ODIM + tj * 16;
#pragma unroll
            for (int i = 0; i < 4; ++i) {   // kk = kq*4 + i, ascending
                float4 w0 = *(const float4*)(wp + (size_t)i * ODIM);
                float4 w1 = *(const float4*)(wp + (size_t)i * ODIM + 4);
                float4 w2 = *(const float4*)(wp + (size_t)i * ODIM + 8);
                float4 w3 = *(const float4*)(wp + (size_t)i * ODIM + 12);
                float ha = (i == 0) ? h0.x : (i == 1) ? h0.y : (i == 2) ? h0.z : h0.w;
                float hb = (i == 0) ? h1.x : (i == 1) ? h1.y : (i == 2) ? h1.z : h1.w;
                acc[0][0]  += ha * w0.x; acc[0][1]  += ha * w0.y;
                acc[0][2]  += ha * w0.z; acc[0][3]  += ha * w0.w;
                acc[0][4]  += ha * w1.x; acc[0][5]  += ha * w1.y;
                acc[0][6]  += ha * w1.z; acc[0][7]  += ha * w1.w;
                acc[0][8]  += ha * w2.x; acc[0][9]  += ha * w2.y;
                acc[0][10] += ha * w2.z; acc[0][11] += ha * w2.w;
                acc[0][12] += ha * w3.x; acc[0][13] += ha * w3.y;
                acc[0][14] += ha * w3.z; acc[0][15] += ha * w3.w;
                acc[1][0]  += hb * w0.x; acc[1][1]  += hb * w0.y;
                acc[1][2]  += hb * w0.z; acc[1][3]  += hb * w0.w;
                acc[1][4]  += hb * w1.x; acc[1][5]  += hb * w1.y;
                acc[1][6]  += hb * w1.z; acc[1][7]  += hb * w1.w;
                acc[1][8]  += hb * w2.x; acc[1][9]  += hb * w2.y;
                acc[1][10] += hb * w2.z; acc[1][11] += hb * w2.w;
                acc[1][12] += hb * w3.x; acc[1][13] += hb * w3.y;
                acc[1][14] += hb * w3.z; acc[1][15] += hb * w3.w;
            }
        }
        __syncthreads();
    }
#pragma unroll
    for (int r = 0; r < 2; ++r) {
        float* op = out + (size_t)(t0 + 2 * ti + r) * ODIM + tj * 16;
        const float* vb = Vb + tj * 16;
#pragma unroll
        for (int c4 = 0; c4 < 4; ++c4) {
            float4 v = *(const float4*)(vb + c4 * 4);
            *(float4*)(op + c4 * 4) = make_float4(
                acc[r][c4 * 4 + 0] + v.x, acc[r][c4 * 4 + 1] + v.y,
                acc[r][c4 * 4 + 2] + v.z, acc[r][c4 * 4 + 3] + v.w);
        }
    }
}

// ---------------------------------------------------------------------------
extern "C" void kernel_launch(void* const* d_in, const int* in_sizes, int n_in,
                              void* d_out, int out_size, void* d_ws, size_t ws_size,
                              hipStream_t stream) {
    const int*   x   = (const int*)d_in[0];
    const float* emb = (const float*)d_in[1];
    const float* W[4] = {(const float*)d_in[2], (const float*)d_in[6],
                         (const float*)d_in[10], (const float*)d_in[14]};
    const float* B[4] = {(const float*)d_in[3], (const float*)d_in[7],
                         (const float*)d_in[11], (const float*)d_in[15]};
    const float* U[4] = {(const float*)d_in[4], (const float*)d_in[8],
                         (const float*)d_in[12], (const float*)d_in[16]};
    const float* C[4] = {(const float*)d_in[5], (const float*)d_in[9],
                         (const float*)d_in[13], (const float*)d_in[17]};
    const float* Vw = (const float*)d_in[18];
    const float* Vb = (const float*)d_in[19];
    float* out = (float*)d_out;

    // ws layout (floats): Zv[256*4*2048] | hs[8192*2048] | pub[2*2048 ull].
    // Poison epoch word 0xAAAAAAAA never equals a live epoch (1..8192), and
    // ws is re-poisoned before every timed call -> no init kernel needed.
    float* ws = (float*)d_ws;
    float* Zv = ws;
    float* hs = Zv + (size_t)VOCAB * 4 * HID;
    unsigned long long* pub = (unsigned long long*)(hs + (size_t)SEQ * HID);

    for (int g = 0; g < 4; ++g)
        k_zv<<<dim3(8, 8), dim3(256), 0, stream>>>(emb, W[g], B[g], C[g], Zv, g);

    float* outTail = out + (size_t)SEQ * ODIM;
    const float *Ui = U[0], *Uf = U[1], *Ugp = U[2], *Uo = U[3];
    const float* Zvc = Zv; const int* xc = x;
    unsigned long long* pubc = pub; float* hsc = hs; float* ot = outTail;
    void* args[9] = {&Ui, &Uf, &Ugp, &Uo, &Zvc, &xc, &pubc, &hsc, &ot};
    hipLaunchCooperativeKernel((void*)k_lstm, dim3(NBLK), dim3(NTHR), args, 0, stream);

    k_out<<<dim3(256), dim3(256), 0, stream>>>(hs, Vw, Vb, out);
}